// Round 6
// baseline (188.586 us; speedup 1.0000x reference)
//
#include <hip/hip_runtime.h>
#include <math.h>

// Problem constants
#define VDIM   128
#define KCODES 512
#define NROWS  (32 * 4096)       // 131072
#define TILE_ROWS 512            // rows per block (8 waves x 64 rows)
#define NBLK (NROWS / TILE_ROWS) // 256 blocks = exactly 1 per CU
#define TN 0.67882250993908565f  // 0.06 * sqrt(128)

typedef __attribute__((ext_vector_type(8))) short bf16x8;  // MFMA A/B frag (4 VGPR)
typedef __attribute__((ext_vector_type(4))) float f32x4;   // MFMA C/D frag / 16B ld-st

__device__ __forceinline__ unsigned short f2bf(float f) {
    unsigned u = __float_as_uint(f);
    unsigned r = u + 0x7FFFu + ((u >> 16) & 1u);   // round-to-nearest-even
    return (unsigned short)(r >> 16);
}

__device__ __forceinline__ bf16x8 pack8(f32x4 a, f32x4 b) {
    bf16x8 v;
    v[0] = (short)f2bf(a[0]); v[1] = (short)f2bf(a[1]);
    v[2] = (short)f2bf(a[2]); v[3] = (short)f2bf(a[3]);
    v[4] = (short)f2bf(b[0]); v[5] = (short)f2bf(b[1]);
    v[6] = (short)f2bf(b[2]); v[7] = (short)f2bf(b[3]);
    return v;
}

// 8 waves x 64 rows, 1 block per CU.
//  - 4 row-strips share each B-fragment read -> per-CU LDS stream halves
//    (1 MB vs 2 MB with 16 waves) and MFMA ILP is 4 independent chains.
//  - x0 loads for strips 0/1 issued at t=0 and PINNED with sched_barrier(0)
//    (launch_bounds alone let the scheduler sink them; VGPR=52 proved it).
//    Strips 2/3 issued after the norm loop so their HBM drain hides under
//    table build + pack01 (vmcnt is in-order per wave: issue order matters).
//  - Shfl-free epilogues: owner lanes ((l&15)>>2 == l>>4) hold exactly the
//    right (best,bidx,nsq) triple for one row each -> direct stores, no
//    ds_bpermute storm (r5: 137k bank conflicts). out0 indices go through a
//    tiny per-wave LDS array (broadcast reads).
// argmin(dist) == argmax(dot(x0,e)) since ||x|| = ||e|| = tn exactly.
__global__ __launch_bounds__(512, 2) void vq_fused(
        const float* __restrict__ x0,
        const float* __restrict__ emb0,
        unsigned short* __restrict__ hist_part,
        float* __restrict__ out0,
        float* __restrict__ out1,
        float* __restrict__ out2) {
    __shared__ uint4 sB[8192];              // 128 KB fragment-linear bf16 table
    __shared__ float sscale[KCODES];        // TN / ||emb0_k||
    __shared__ int   shist[KCODES];         // per-block histogram
    __shared__ int   sbesti[TILE_ROWS];     // per-row winning code

    int t = threadIdx.x;
    int w = t >> 6;           // wave 0..7
    int l = t & 63;
    int n15 = l & 15;         // MFMA m (A rows), n (B cols), col (C)
    int q = l >> 4;           // quad: input k = q*8 + j; C row = q*4 + r

    int rowbase = blockIdx.x * TILE_ROWS + (w << 6);   // 64 rows per wave

    // ---- Issue strips 0,1 x0 loads NOW; sched_barrier pins issue order.
    f32x4 ax01[2][4][2];
    #pragma unroll
    for (int s = 0; s < 2; ++s) {
        const float* xrow = x0 + (size_t)(rowbase + (s << 4) + n15) * VDIM + (q << 3);
        #pragma unroll
        for (int kc = 0; kc < 4; ++kc) {
            const f32x4* xp = (const f32x4*)(xrow + (kc << 5));
            ax01[s][kc][0] = xp[0];
            ax01[s][kc][1] = xp[1];
        }
    }
    __builtin_amdgcn_sched_barrier(0);

    if (t < KCODES) shist[t] = 0;

    // ---- Norm phase: wave w computes codes w*64 .. w*64+63.
    #pragma unroll 4
    for (int i = 0; i < 64; ++i) {
        int k = (w << 6) + i;
        const float* row = emb0 + (size_t)k * VDIM;
        float a = row[l];
        float b = row[l + 64];
        float ss = a * a + b * b;
        #pragma unroll
        for (int off = 32; off; off >>= 1) ss += __shfl_xor(ss, off);
        if (l == 0) sscale[k] = TN / sqrtf(ss);
    }

    // ---- Issue strips 2,3 x0 loads (drain hides under table build + pack01)
    f32x4 ax23[2][4][2];
    #pragma unroll
    for (int s = 0; s < 2; ++s) {
        const float* xrow = x0 + (size_t)(rowbase + ((s + 2) << 4) + n15) * VDIM + (q << 3);
        #pragma unroll
        for (int kc = 0; kc < 4; ++kc) {
            const f32x4* xp = (const f32x4*)(xrow + (kc << 5));
            ax23[s][kc][0] = xp[0];
            ax23[s][kc][1] = xp[1];
        }
    }
    __builtin_amdgcn_sched_barrier(0);

    __syncthreads();        // sscale + shist-zero visible

    // ---- Table build: granule g holds dims [d0,d0+8) of code k,
    //   k = (g>>8)*16 + (g&15),  d0 = ((g>>4)&15)*8.  16 granules/thread.
    #pragma unroll
    for (int i = 0; i < 16; ++i) {
        int g = (i << 9) + t;
        int k = ((g >> 8) << 4) | (g & 15);
        int d0 = ((g >> 4) & 15) << 3;
        float s = sscale[k];
        const f32x4* ep = (const f32x4*)(emb0 + (size_t)k * VDIM + d0);
        f32x4 a = ep[0], b = ep[1];
        f32x4 as, bs;
        as[0] = a[0] * s; as[1] = a[1] * s; as[2] = a[2] * s; as[3] = a[3] * s;
        bs[0] = b[0] * s; bs[1] = b[1] * s; bs[2] = b[2] * s; bs[3] = b[3] * s;
        ((bf16x8*)sB)[g] = pack8(as, bs);
    }

    // ---- Pack strips 0,1 (loads long since arrived)
    bf16x8 afr[4][4];
    float nsq[4];
    #pragma unroll
    for (int s = 0; s < 2; ++s) {
        float p0 = 0.f, p1 = 0.f;
        #pragma unroll
        for (int kc = 0; kc < 4; ++kc) {
            f32x4 a = ax01[s][kc][0], b = ax01[s][kc][1];
            p0 = fmaf(a[0], a[0], p0); p1 = fmaf(a[1], a[1], p1);
            p0 = fmaf(a[2], a[2], p0); p1 = fmaf(a[3], a[3], p1);
            p0 = fmaf(b[0], b[0], p0); p1 = fmaf(b[1], b[1], p1);
            p0 = fmaf(b[2], b[2], p0); p1 = fmaf(b[3], b[3], p1);
            afr[s][kc] = pack8(a, b);
        }
        nsq[s] = p0 + p1;
        nsq[s] += __shfl_xor(nsq[s], 16, 64);
        nsq[s] += __shfl_xor(nsq[s], 32, 64);
    }

    __syncthreads();        // table fully built; last block-wide sync before tail

    // ---- Pack strips 2,3
    #pragma unroll
    for (int s = 0; s < 2; ++s) {
        float p0 = 0.f, p1 = 0.f;
        #pragma unroll
        for (int kc = 0; kc < 4; ++kc) {
            f32x4 a = ax23[s][kc][0], b = ax23[s][kc][1];
            p0 = fmaf(a[0], a[0], p0); p1 = fmaf(a[1], a[1], p1);
            p0 = fmaf(a[2], a[2], p0); p1 = fmaf(a[3], a[3], p1);
            p0 = fmaf(b[0], b[0], p0); p1 = fmaf(b[1], b[1], p1);
            p0 = fmaf(b[2], b[2], p0); p1 = fmaf(b[3], b[3], p1);
            afr[s + 2][kc] = pack8(a, b);
        }
        nsq[s + 2] = p0 + p1;
        nsq[s + 2] += __shfl_xor(nsq[s + 2], 16, 64);
        nsq[s + 2] += __shfl_xor(nsq[s + 2], 32, 64);
    }

    float best[4][4];
    int   bidx[4][4];
    #pragma unroll
    for (int s = 0; s < 4; ++s)
        #pragma unroll
        for (int r = 0; r < 4; ++r) { best[s][r] = -3.4e38f; bidx[s][r] = 0; }

    const f32x4 zero4 = {0.f, 0.f, 0.f, 0.f};

    // ---- 32 chunks of 16 codes; each B frag feeds 4 strips (16 MFMA/chunk)
    #pragma unroll 2
    for (int cn = 0; cn < 32; ++cn) {
        const bf16x8* bls = ((const bf16x8*)sB) + (cn << 8) + l;
        bf16x8 b0 = bls[0], b1 = bls[64], b2 = bls[128], b3 = bls[192];
        int nbase = (cn << 4) + n15;
        #pragma unroll
        for (int s = 0; s < 4; ++s) {
            f32x4 acc = __builtin_amdgcn_mfma_f32_16x16x32_bf16(afr[s][0], b0, zero4, 0, 0, 0);
            acc = __builtin_amdgcn_mfma_f32_16x16x32_bf16(afr[s][1], b1, acc, 0, 0, 0);
            acc = __builtin_amdgcn_mfma_f32_16x16x32_bf16(afr[s][2], b2, acc, 0, 0, 0);
            acc = __builtin_amdgcn_mfma_f32_16x16x32_bf16(afr[s][3], b3, acc, 0, 0, 0);
            #pragma unroll
            for (int r = 0; r < 4; ++r) {
                float d = acc[r];
                if (d > best[s][r]) { best[s][r] = d; bidx[s][r] = nbase; }
            }
        }
    }

    // ---- Reduce argmax across the 16 lanes (C cols) holding the same row
    #pragma unroll
    for (int m = 1; m <= 8; m <<= 1) {
        #pragma unroll
        for (int s = 0; s < 4; ++s)
            #pragma unroll
            for (int r = 0; r < 4; ++r) {
                float ov = __shfl_xor(best[s][r], m, 64);
                int   oi = __shfl_xor(bidx[s][r], m, 64);
                if (ov > best[s][r] || (ov == best[s][r] && oi < bidx[s][r])) {
                    best[s][r] = ov; bidx[s][r] = oi;
                }
            }
    }

    // ---- Owner-lane epilogue (no shfl): lane l = 20*q'+r holds exactly
    // row (s<<4)+(l&15)'s (best,bidx) in slot [s][l&3] AND its nsq[s].
    // 16 owner lanes per strip write out1/out2/hist/sbesti directly.
    int r3 = l & 3;
    bool own = (((l & 15) >> 2) == q);
    if (own) {
        #pragma unroll
        for (int s = 0; s < 4; ++s) {
            int rl = (s << 4) + (l & 15);
            size_t row = (size_t)rowbase + rl;
            float dv = best[s][r3];
            int   bv = bidx[s][r3];
            float nn = nsq[s];
            float sc = TN / sqrtf(nn);                   // x = sc * x0
            float o1 = 2.f * TN * TN - 2.f * sc * dv;    // ||x||=||e||=tn
            __builtin_nontemporal_store(o1, &out1[row]);
            float sm = sc - 1.f;
            __builtin_nontemporal_store(o1 + sm * sm * nn, &out2[row]);
            atomicAdd(&shist[bv], 1);
            sbesti[(w << 6) + rl] = bv;
        }
    }

    // ---- Wave-local out0: 32 passes x 2 rows (64 lanes x 16B contiguous).
    // bi via LDS broadcast of this wave's own sbesti entries (no barrier:
    // same-wave RAW, compiler inserts the lgkmcnt wait).
    #pragma unroll 8
    for (int p = 0; p < 32; ++p) {
        int rl = (p << 1) + (l >> 5);
        int bi = sbesti[(w << 6) + rl];
        float s = sscale[bi];
        int v4 = l & 31;
        f32x4 e = *((const f32x4*)(emb0 + (size_t)bi * VDIM) + v4);
        f32x4 o;
        o[0] = e[0] * s; o[1] = e[1] * s; o[2] = e[2] * s; o[3] = e[3] * s;
        __builtin_nontemporal_store(
            o, (f32x4*)(out0 + ((size_t)rowbase + rl) * (size_t)VDIM) + v4);
    }

    __syncthreads();        // all waves' histogram contributions landed

    // ---- Write u16 histogram partial (counts <= 512 fit u16); no atomics.
    if (t < KCODES)
        hist_part[((size_t)blockIdx.x << 9) + t] = (unsigned short)shist[t];
}

// Sum 256 x 512 u16 partials (256 KB) and compute entropy. One block.
__global__ __launch_bounds__(1024) void entropy_k(
        const unsigned short* __restrict__ hp,
        float* __restrict__ out) {
    __shared__ int   s2[1024];
    __shared__ float red[8];
    int t = threadIdx.x;
    int c = t & 511;          // code
    int half = t >> 9;        // each half sums 128 blocks
    int sum = 0;
    #pragma unroll 8
    for (int b = half * 128; b < half * 128 + 128; ++b)
        sum += hp[(b << 9) + c];
    s2[t] = sum;
    __syncthreads();
    if (t < 512) {
        float h = (float)(s2[t] + s2[t + 512]);
        float p = h / (float)NROWS;
        float term = (h > 0.f) ? p * logf(p) : 0.f;
        #pragma unroll
        for (int off = 32; off; off >>= 1) term += __shfl_xor(term, off);
        if ((t & 63) == 0) red[t >> 6] = term;
    }
    __syncthreads();
    if (t == 0) {
        float ssum = 0.f;
        #pragma unroll
        for (int i = 0; i < 8; i++) ssum += red[i];
        out[0] = -ssum;
    }
}

extern "C" void kernel_launch(void* const* d_in, const int* in_sizes, int n_in,
                              void* d_out, int out_size, void* d_ws, size_t ws_size,
                              hipStream_t stream) {
    const float* x0   = (const float*)d_in[0];
    const float* emb0 = (const float*)d_in[1];

    unsigned short* hist_part = (unsigned short*)d_ws;   // 256*512*2 = 256 KB

    float* out  = (float*)d_out;
    float* out0 = out;
    float* out1 = out0 + (size_t)NROWS * VDIM;
    float* out2 = out1 + NROWS;
    float* oent = out2 + NROWS;

    vq_fused<<<NBLK, 512, 0, stream>>>(x0, emb0, hist_part, out0, out1, out2);
    entropy_k<<<1, 1024, 0, stream>>>(hist_part, oent);
}

// Round 7
// 157.809 us; speedup vs baseline: 1.1950x; 1.1950x over previous
//
#include <hip/hip_runtime.h>
#include <math.h>

// Problem constants
#define VDIM   128
#define KCODES 512
#define NROWS  (32 * 4096)       // 131072
#define TILE_ROWS 512            // rows per block (16 waves x 32 rows)
#define NBLK (NROWS / TILE_ROWS) // 256 blocks = exactly 1 per CU
#define TN 0.67882250993908565f  // 0.06 * sqrt(128)

typedef __attribute__((ext_vector_type(8))) short bf16x8;  // MFMA A/B frag (4 VGPR)
typedef __attribute__((ext_vector_type(4))) float f32x4;   // MFMA C/D frag / 16B ld-st

__device__ __forceinline__ unsigned short f2bf(float f) {
    unsigned u = __float_as_uint(f);
    unsigned r = u + 0x7FFFu + ((u >> 16) & 1u);   // round-to-nearest-even
    return (unsigned short)(r >> 16);
}

__device__ __forceinline__ bf16x8 pack8(f32x4 a, f32x4 b) {
    bf16x8 v;
    v[0] = (short)f2bf(a[0]); v[1] = (short)f2bf(a[1]);
    v[2] = (short)f2bf(a[2]); v[3] = (short)f2bf(a[3]);
    v[4] = (short)f2bf(b[0]); v[5] = (short)f2bf(b[1]);
    v[6] = (short)f2bf(b[2]); v[7] = (short)f2bf(b[3]);
    return v;
}

// 16 waves x 32 rows, 1 block per CU (r5 structure, best measured: 67 us).
// Changes vs r5:
//  - x0 loads for BOTH strips issued at t=0 behind ONE sched_barrier(0).
//    vmcnt is in-order per wave, so the norm phase's first emb0 consume
//    implies the x0 stream drains FIRST at full HBM BW, overlapped with /
//    ahead of the L2-warm norm+table phases -- instead of a cold serial
//    burst at pack time (r5: VGPR=52 proved the loads were being sunk).
//    Consumers (pack) are deliberately NOT pinned (r6's over-pinning made
//    the compiler hoist pack and stall early).
//  - Owner-lane epilogue (r6-verified): lane l with (l&15)>>2 == q owns
//    row (s<<4)+(l&15) -- its (best,bidx) sit in slot [s][l&3] and its nsq[s]
//    is that row's norm. Direct stores, no variable-lane shfl (r5's
//    ds_bpermute storm: 137k bank conflicts -> ~11k).
// argmin(dist) == argmax(dot(x0,e)) since ||x|| = ||e|| = tn exactly.
__global__ __launch_bounds__(1024, 1) void vq_fused(
        const float* __restrict__ x0,
        const float* __restrict__ emb0,
        unsigned short* __restrict__ hist_part,
        float* __restrict__ out0,
        float* __restrict__ out1,
        float* __restrict__ out2) {
    __shared__ uint4 sB[8192];              // 128 KB fragment-linear bf16 table
    __shared__ float sscale[KCODES];        // TN / ||emb0_k||
    __shared__ int   shist[KCODES];         // per-block histogram
    __shared__ int   sbesti[TILE_ROWS];     // per-row winning code

    int t = threadIdx.x;
    int w = t >> 6;           // wave 0..15
    int l = t & 63;
    int n15 = l & 15;         // MFMA m (A rows), n (B cols), col (C)
    int q = l >> 4;           // quad: input k = q*8 + j; C row = q*4 + r

    int rowbase = blockIdx.x * TILE_ROWS + (w << 5);   // 32 rows per wave

    // ---- Issue BOTH strips' x0 loads FIRST; sched_barrier pins issue order.
    f32x4 ax[2][4][2];
    #pragma unroll
    for (int s = 0; s < 2; ++s) {
        const float* xrow = x0 + (size_t)(rowbase + (s << 4) + n15) * VDIM + (q << 3);
        #pragma unroll
        for (int kc = 0; kc < 4; ++kc) {
            const f32x4* xp = (const f32x4*)(xrow + (kc << 5));
            ax[s][kc][0] = xp[0];
            ax[s][kc][1] = xp[1];
        }
    }
    __builtin_amdgcn_sched_barrier(0);

    if (t < KCODES) shist[t] = 0;

    // ---- Norm phase: wave w computes codes w*32 .. w*32+31. Its first
    // emb0 consume forces the (older) x0 loads to land -> x0 drain happens
    // here, at full BW, while shfl-chains execute.
    #pragma unroll 4
    for (int i = 0; i < 32; ++i) {
        int k = (w << 5) + i;
        const float* row = emb0 + (size_t)k * VDIM;
        float a = row[l];
        float b = row[l + 64];
        float ss = a * a + b * b;
        #pragma unroll
        for (int off = 32; off; off >>= 1) ss += __shfl_xor(ss, off);
        if (l == 0) sscale[k] = TN / sqrtf(ss);
    }

    __syncthreads();        // sscale + shist-zero visible

    // ---- Table build: granule g holds dims [d0,d0+8) of code k,
    //   k = (g>>8)*16 + (g&15),  d0 = ((g>>4)&15)*8.  8 granules/thread.
    #pragma unroll
    for (int i = 0; i < 8; ++i) {
        int g = (i << 10) + t;
        int k = ((g >> 8) << 4) | (g & 15);
        int d0 = ((g >> 4) & 15) << 3;
        float s = sscale[k];
        const f32x4* ep = (const f32x4*)(emb0 + (size_t)k * VDIM + d0);
        f32x4 a = ep[0], b = ep[1];
        f32x4 as, bs;
        as[0] = a[0] * s; as[1] = a[1] * s; as[2] = a[2] * s; as[3] = a[3] * s;
        bs[0] = b[0] * s; bs[1] = b[1] * s; bs[2] = b[2] * s; bs[3] = b[3] * s;
        ((bf16x8*)sB)[g] = pack8(as, bs);
    }

    // ---- Pack A (x0 data long since arrived)
    bf16x8 afr[2][4];
    float nsq[2];
    #pragma unroll
    for (int s = 0; s < 2; ++s) {
        float p0 = 0.f, p1 = 0.f;
        #pragma unroll
        for (int kc = 0; kc < 4; ++kc) {
            f32x4 a = ax[s][kc][0], b = ax[s][kc][1];
            p0 = fmaf(a[0], a[0], p0); p1 = fmaf(a[1], a[1], p1);
            p0 = fmaf(a[2], a[2], p0); p1 = fmaf(a[3], a[3], p1);
            p0 = fmaf(b[0], b[0], p0); p1 = fmaf(b[1], b[1], p1);
            p0 = fmaf(b[2], b[2], p0); p1 = fmaf(b[3], b[3], p1);
            afr[s][kc] = pack8(a, b);
        }
        nsq[s] = p0 + p1;
        nsq[s] += __shfl_xor(nsq[s], 16, 64);   // row (s<<4)+n15 full norm^2
        nsq[s] += __shfl_xor(nsq[s], 32, 64);
    }

    float best[2][4];
    int   bidx[2][4];
    #pragma unroll
    for (int s = 0; s < 2; ++s)
        #pragma unroll
        for (int r = 0; r < 4; ++r) { best[s][r] = -3.4e38f; bidx[s][r] = 0; }

    const f32x4 zero4 = {0.f, 0.f, 0.f, 0.f};

    __syncthreads();        // table fully built; last block-wide sync before tail

    // ---- 32 chunks of 16 codes, B frags from LDS (stride-1, conflict-free)
    #pragma unroll 2
    for (int cn = 0; cn < 32; ++cn) {
        const bf16x8* bls = ((const bf16x8*)sB) + (cn << 8) + l;
        bf16x8 b0 = bls[0], b1 = bls[64], b2 = bls[128], b3 = bls[192];
        int nbase = (cn << 4) + n15;
        #pragma unroll
        for (int s = 0; s < 2; ++s) {
            f32x4 acc = __builtin_amdgcn_mfma_f32_16x16x32_bf16(afr[s][0], b0, zero4, 0, 0, 0);
            acc = __builtin_amdgcn_mfma_f32_16x16x32_bf16(afr[s][1], b1, acc, 0, 0, 0);
            acc = __builtin_amdgcn_mfma_f32_16x16x32_bf16(afr[s][2], b2, acc, 0, 0, 0);
            acc = __builtin_amdgcn_mfma_f32_16x16x32_bf16(afr[s][3], b3, acc, 0, 0, 0);
            #pragma unroll
            for (int r = 0; r < 4; ++r) {
                float d = acc[r];
                if (d > best[s][r]) { best[s][r] = d; bidx[s][r] = nbase; }
            }
        }
    }

    // ---- Reduce argmax across the 16 lanes (C cols) holding the same row.
    // Afterwards lanes {q*16+0..15} hold identical results for rows q*4+r.
    #pragma unroll
    for (int m = 1; m <= 8; m <<= 1) {
        #pragma unroll
        for (int s = 0; s < 2; ++s)
            #pragma unroll
            for (int r = 0; r < 4; ++r) {
                float ov = __shfl_xor(best[s][r], m, 64);
                int   oi = __shfl_xor(bidx[s][r], m, 64);
                if (ov > best[s][r] || (ov == best[s][r] && oi < bidx[s][r])) {
                    best[s][r] = ov; bidx[s][r] = oi;
                }
            }
    }

    // ---- Owner-lane epilogue (no shfl): lane l with (l&15)>>2 == q owns
    // rows (s<<4)+(l&15); its result is slot [s][l&3], its norm is nsq[s].
    int r3 = l & 3;
    bool own = (((l & 15) >> 2) == q);
    if (own) {
        #pragma unroll
        for (int s = 0; s < 2; ++s) {
            int rl = (s << 4) + (l & 15);
            size_t row = (size_t)rowbase + rl;
            float dv = best[s][r3];
            int   bv = bidx[s][r3];
            float nn = nsq[s];
            float sc = TN / sqrtf(nn);                   // x = sc * x0
            float o1 = 2.f * TN * TN - 2.f * sc * dv;    // ||x||=||e||=tn
            __builtin_nontemporal_store(o1, &out1[row]);
            float sm = sc - 1.f;
            __builtin_nontemporal_store(o1 + sm * sm * nn, &out2[row]);
            atomicAdd(&shist[bv], 1);
            sbesti[(w << 5) + rl] = bv;
        }
    }

    // ---- Wave-local out0: 16 passes x 2 rows (64 lanes x 16B contiguous).
    // bi via LDS broadcast of this wave's own sbesti entries (same-wave RAW,
    // compiler inserts the lgkmcnt wait; no barrier needed).
    #pragma unroll 4
    for (int p = 0; p < 16; ++p) {
        int rl = (p << 1) + (l >> 5);
        int bi = sbesti[(w << 5) + rl];
        float s = sscale[bi];
        int v4 = l & 31;
        f32x4 e = *((const f32x4*)(emb0 + (size_t)bi * VDIM) + v4);
        f32x4 o;
        o[0] = e[0] * s; o[1] = e[1] * s; o[2] = e[2] * s; o[3] = e[3] * s;
        __builtin_nontemporal_store(
            o, (f32x4*)(out0 + ((size_t)rowbase + rl) * (size_t)VDIM) + v4);
    }

    __syncthreads();        // all waves' histogram contributions landed

    // ---- Write u16 histogram partial (counts <= 512 fit u16); no atomics.
    if (t < KCODES)
        hist_part[((size_t)blockIdx.x << 9) + t] = (unsigned short)shist[t];
}

// Sum 256 x 512 u16 partials (256 KB) and compute entropy. One block.
__global__ __launch_bounds__(1024) void entropy_k(
        const unsigned short* __restrict__ hp,
        float* __restrict__ out) {
    __shared__ int   s2[1024];
    __shared__ float red[8];
    int t = threadIdx.x;
    int c = t & 511;          // code
    int half = t >> 9;        // each half sums 128 blocks
    int sum = 0;
    #pragma unroll 8
    for (int b = half * 128; b < half * 128 + 128; ++b)
        sum += hp[(b << 9) + c];
    s2[t] = sum;
    __syncthreads();
    if (t < 512) {
        float h = (float)(s2[t] + s2[t + 512]);
        float p = h / (float)NROWS;
        float term = (h > 0.f) ? p * logf(p) : 0.f;
        #pragma unroll
        for (int off = 32; off; off >>= 1) term += __shfl_xor(term, off);
        if ((t & 63) == 0) red[t >> 6] = term;
    }
    __syncthreads();
    if (t == 0) {
        float ssum = 0.f;
        #pragma unroll
        for (int i = 0; i < 8; i++) ssum += red[i];
        out[0] = -ssum;
    }
}

extern "C" void kernel_launch(void* const* d_in, const int* in_sizes, int n_in,
                              void* d_out, int out_size, void* d_ws, size_t ws_size,
                              hipStream_t stream) {
    const float* x0   = (const float*)d_in[0];
    const float* emb0 = (const float*)d_in[1];

    unsigned short* hist_part = (unsigned short*)d_ws;   // 256*512*2 = 256 KB

    float* out  = (float*)d_out;
    float* out0 = out;
    float* out1 = out0 + (size_t)NROWS * VDIM;
    float* out2 = out1 + NROWS;
    float* oent = out2 + NROWS;

    vq_fused<<<NBLK, 1024, 0, stream>>>(x0, emb0, hist_part, out0, out1, out2);
    entropy_k<<<1, 1024, 0, stream>>>(hist_part, oent);
}